// Round 1
// baseline (682.112 us; speedup 1.0000x reference)
//
#include <hip/hip_runtime.h>

// Problem constants (fixed by setup_inputs): b=16, s=4096, h=16, p=64, n=64
constexpr int S  = 4096;
constexpr int H  = 16;
constexpr int P  = 64;
constexpr int NN = 64;
constexpr int PAIRS = 256;          // b*h
constexpr int KSPLIT = 8;           // K-dim split across blocks
constexpr int KCHUNK = S / KSPLIT;  // 512
constexpr int TT = 16;              // t-rows staged per LDS tile

// Kernel 1: per (b,h) pair, w[t] = exp(total_sum - inclusive_prefix(t))
//           = exp(sum of A over positions t+1 .. s-1)
__global__ __launch_bounds__(256) void scan_w(const float* __restrict__ A,
                                              float* __restrict__ w) {
    const int pair = blockIdx.x;          // 0..255
    const int b = pair >> 4, h = pair & 15;
    const float* Ab = A + (size_t)b * S * H + h;   // element t at Ab[t*H]
    const int j = threadIdx.x;            // 0..255, owns t in [j*16, j*16+16)

    float a[16];
    float lsum = 0.f;
#pragma unroll
    for (int i = 0; i < 16; ++i) {
        a[i] = Ab[(size_t)(j * 16 + i) * H];
        lsum += a[i];
    }

    __shared__ float sd[256];
    sd[j] = lsum;
    __syncthreads();
    float incl = lsum;
    for (int off = 1; off < 256; off <<= 1) {
        float add = (j >= off) ? sd[j - off] : 0.f;
        __syncthreads();
        incl += add;
        sd[j] = incl;
        __syncthreads();
    }
    const float total = sd[255];
    float run = incl - lsum;  // exclusive prefix at this thread's first element

    float* wrow = w + (size_t)pair * S + j * 16;
#pragma unroll
    for (int i = 0; i < 16; ++i) {
        run += a[i];
        wrow[i] = expf(total - run);  // underflows to 0 for early t: fine
    }
}

// Kernel 2: out[pair][p][n] += sum_t w[t] * X[t][p] * B[t][n]  (K-split, atomic)
__global__ __launch_bounds__(256) void mainK(const float* __restrict__ X,
                                             const float* __restrict__ Bm,
                                             const float* __restrict__ w,
                                             float* __restrict__ out) {
    const int pair = blockIdx.x;   // 0..255
    const int ks   = blockIdx.y;   // 0..KSPLIT-1
    const int b = pair >> 4, h = pair & 15;

    const float* Xp   = X  + (size_t)b * S * H * P  + (size_t)h * P;   // + t*(H*P) + p
    const float* Bp   = Bm + (size_t)b * S * H * NN + (size_t)h * NN;  // + t*(H*NN) + n
    const float* wrow = w  + (size_t)pair * S;
    const int t0base = ks * KCHUNK;

    __shared__ float Xs[TT][P];   // X rows pre-scaled by w
    __shared__ float Bs[TT][NN];

    const int tid = threadIdx.x;
    const int row = tid >> 4;         // 0..15  (staging row)
    const int c4  = (tid & 15) * 4;   // 0..60  (staging col, float4)

    const int tp = (tid >> 4) * 4;    // p0 of this thread's 4x4 tile
    const int tn = (tid & 15) * 4;    // n0

    float acc[4][4];
#pragma unroll
    for (int i = 0; i < 4; ++i)
#pragma unroll
        for (int j = 0; j < 4; ++j) acc[i][j] = 0.f;

    for (int t0 = t0base; t0 < t0base + KCHUNK; t0 += TT) {
        const int t = t0 + row;
        const float wv = wrow[t];  // 16-way duplicate load, L1-cached
        const float4 xv = *(const float4*)(Xp + (size_t)t * (H * P)  + c4);
        const float4 bv = *(const float4*)(Bp + (size_t)t * (H * NN) + c4);
        __syncthreads();  // previous tile's compute done before overwrite
        *(float4*)(&Xs[row][c4]) = make_float4(xv.x * wv, xv.y * wv, xv.z * wv, xv.w * wv);
        *(float4*)(&Bs[row][c4]) = bv;
        __syncthreads();
#pragma unroll
        for (int r = 0; r < TT; ++r) {
            const float4 xr = *(const float4*)(&Xs[r][tp]);  // broadcast within lane groups
            const float4 br = *(const float4*)(&Bs[r][tn]);
            const float xa[4] = {xr.x, xr.y, xr.z, xr.w};
            const float ba[4] = {br.x, br.y, br.z, br.w};
#pragma unroll
            for (int i = 0; i < 4; ++i)
#pragma unroll
                for (int j = 0; j < 4; ++j)
                    acc[i][j] = fmaf(xa[i], ba[j], acc[i][j]);
        }
    }

    float* op = out + (size_t)pair * (P * NN);
#pragma unroll
    for (int i = 0; i < 4; ++i)
#pragma unroll
        for (int j = 0; j < 4; ++j)
            atomicAdd(&op[(size_t)(tp + i) * NN + tn + j], acc[i][j]);
}

extern "C" void kernel_launch(void* const* d_in, const int* in_sizes, int n_in,
                              void* d_out, int out_size, void* d_ws, size_t ws_size,
                              hipStream_t stream) {
    const float* X = (const float*)d_in[0];
    const float* A = (const float*)d_in[1];
    const float* B = (const float*)d_in[2];
    // d_in[3] = C is computed-then-discarded by the reference: never read.
    float* out = (float*)d_out;
    float* w   = (float*)d_ws;  // PAIRS*S floats = 4 MiB scratch

    hipMemsetAsync(d_out, 0, (size_t)out_size * sizeof(float), stream);
    scan_w<<<PAIRS, 256, 0, stream>>>(A, w);
    mainK<<<dim3(PAIRS, KSPLIT), 256, 0, stream>>>(X, B, w, out);
}